// Round 8
// baseline (110.304 us; speedup 1.0000x reference)
//
#include <hip/hip_runtime.h>

#define BATCH   65536
#define IN_DIM  784
#define HDIM    20
#define NCLS    10
#define THREADS 512           // 8 waves: 4 sample-groups x 2 K-halves
#define SPW     16            // samples per wave (MFMA M)
#define SPB     64            // samples per block
#define PSTRIDE 49            // LDS pre-act row stride (conflict-free)
#define W1ELEMS (10 * HDIM * IN_DIM)   // 156800
#define KHALF   384           // K split: [0,384) and [384,784)

typedef __attribute__((ext_vector_type(2))) __fp16   fp16x2;   // cvt_pkrtz result type
typedef __attribute__((ext_vector_type(8))) _Float16 f16x8;    // MFMA operand type
typedef __attribute__((ext_vector_type(4))) float    f32x4;

typedef union { uint4 q; f16x8 v; } BFrag;
typedef union { fp16x2 h[4]; f16x8 v; } AFrag;
typedef union { fp16x2 h[2]; uint2 u; } Pack4;

struct Stage {
    float a[8];
    uint4 b[3];
};

// sorted(set(row))[:2] -> (e0, e1, mask). mask=0 when only one unique module.
__device__ __forceinline__ void route(const int* pw, bool is64, int row,
                                      int& e0, int& e1, float& m) {
    int v0, v1, v2;
    if (is64) {
        v0 = pw[(row * 3 + 0) * 2];
        v1 = pw[(row * 3 + 1) * 2];
        v2 = pw[(row * 3 + 2) * 2];
    } else {
        v0 = pw[row * 3 + 0];
        v1 = pw[row * 3 + 1];
        v2 = pw[row * 3 + 2];
    }
    int lo  = min(v0, min(v1, v2));
    int hi  = max(v0, max(v1, v2));
    int mid = v0 + v1 + v2 - lo - hi;
    e0 = lo;
    if (mid != lo)     { e1 = mid; m = 1.0f; }
    else if (hi != lo) { e1 = hi;  m = 1.0f; }
    else               { e1 = lo;  m = 0.0f; }
}

// gather the 4 per-lane 5-slices into a full 20-vector (static indexing)
__device__ __forceinline__ void gather20(const float my5[5], int ksub,
                                         float outv[HDIM]) {
    float r1[5];
#pragma unroll
    for (int j = 0; j < 5; ++j) r1[j] = __shfl_xor(my5[j], 1, 64);
    const bool b0 = (ksub & 1);
    float q[10];
#pragma unroll
    for (int j = 0; j < 5; ++j) {
        q[j]     = b0 ? r1[j]  : my5[j];
        q[5 + j] = b0 ? my5[j] : r1[j];
    }
    float r2[10];
#pragma unroll
    for (int j = 0; j < 10; ++j) r2[j] = __shfl_xor(q[j], 2, 64);
    const bool b1 = (ksub & 2);
#pragma unroll
    for (int j = 0; j < 10; ++j) {
        outv[j]      = b1 ? r2[j] : q[j];
        outv[10 + j] = b1 ? q[j]  : r2[j];
    }
}

// ---- pre-kernel: W1 (fp32) -> fp16, same [e][o][k] layout ----
__global__ __launch_bounds__(256)
void cvt_w1_kernel(const float* __restrict__ W1, _Float16* __restrict__ Wh) {
    const int i = (blockIdx.x * 256 + threadIdx.x) * 4;
    if (i < W1ELEMS) {
        const float4 v = *reinterpret_cast<const float4*>(W1 + i);
        Pack4 pk;
        pk.h[0] = __builtin_amdgcn_cvt_pkrtz(v.x, v.y);
        pk.h[1] = __builtin_amdgcn_cvt_pkrtz(v.z, v.w);
        *reinterpret_cast<uint2*>(Wh + i) = pk.u;
    }
}

// stage loads at byte offset k0; full=false means 16-wide tail (kg<2 loads,
// kg>=2 zeros). `full` is constant-folded inside the unrolled caller.
__device__ __forceinline__ void loadStage(bool full, int k0, int kg,
                                          const float* __restrict__ aptr,
                                          const _Float16* const bptr[3],
                                          Stage& st) {
    if (full || kg < 2) {
        const float4 q0 = *reinterpret_cast<const float4*>(aptr + k0);
        const float4 q1 = *reinterpret_cast<const float4*>(aptr + k0 + 4);
        st.a[0] = q0.x; st.a[1] = q0.y; st.a[2] = q0.z; st.a[3] = q0.w;
        st.a[4] = q1.x; st.a[5] = q1.y; st.a[6] = q1.z; st.a[7] = q1.w;
#pragma unroll
        for (int tt = 0; tt < 3; ++tt)
            st.b[tt] = *reinterpret_cast<const uint4*>(bptr[tt] + k0);
    } else {
#pragma unroll
        for (int j = 0; j < 8; ++j) st.a[j] = 0.0f;
#pragma unroll
        for (int tt = 0; tt < 3; ++tt)
            st.b[tt] = make_uint4(0, 0, 0, 0);
    }
}

__device__ __forceinline__ void computeStep(const Stage& st, f32x4 acc[3]) {
    AFrag a;
#pragma unroll
    for (int j = 0; j < 4; ++j)
        a.h[j] = __builtin_amdgcn_cvt_pkrtz(st.a[2 * j], st.a[2 * j + 1]);
#pragma unroll
    for (int tt = 0; tt < 3; ++tt) {
        BFrag b;
        b.q = st.b[tt];
        acc[tt] = __builtin_amdgcn_mfma_f32_16x16x32_f16(a.v, b.v, acc[tt], 0, 0, 0);
    }
}

// Steps 0..NST-1 of width 32; steps >= NFULLS are 16-wide tails.
// Depth-3 software pipeline, fully unrolled (static stage indices).
template<int NST, int NFULLS>
__device__ __forceinline__ void gemmLoop(const float* __restrict__ aptr,
                                         const _Float16* const bptr[3],
                                         int kg, f32x4 acc[3]) {
    Stage st[3];
    loadStage(0 < NFULLS, 0, kg, aptr, bptr, st[0]);
    if (NST > 1) loadStage(1 < NFULLS, 32, kg, aptr, bptr, st[1]);
#pragma unroll
    for (int i = 0; i < NST; ++i) {
        if (i + 2 < NST)
            loadStage(i + 2 < NFULLS, (i + 2) * 32, kg, aptr, bptr, st[(i + 2) % 3]);
        computeStep(st[i % 3], acc);
    }
}

__global__ __launch_bounds__(THREADS, 8)
void pathnet_kernel(const float* __restrict__ x,
                    const _Float16* __restrict__ Wh, const float* __restrict__ b1,
                    const float* __restrict__ W2, const float* __restrict__ b2,
                    const float* __restrict__ W3, const float* __restrict__ b3,
                    const float* __restrict__ Wl, const float* __restrict__ bl,
                    const int*   __restrict__ pathway,
                    float* __restrict__ out)
{
    __shared__ float preLds[8][SPW][PSTRIDE];   // 24.5 KB

    const int t    = threadIdx.x;
    const int lane = t & 63;
    const int w    = __builtin_amdgcn_readfirstlane(t >> 6);   // 0..7
    const int g    = w & 3;                     // sample group
    const int half = w >> 2;                    // K half

    // ---- routing (uniform) ----
    bool is64 = ((pathway[1] | pathway[3] | pathway[5] | pathway[7]) == 0);
    int e10, e11, e20, e21, e30, e31;
    float m1, m2, m3;
    route(pathway, is64, 0, e10, e11, m1);
    route(pathway, is64, 1, e20, e21, m2);
    route(pathway, is64, 2, e30, e31, m3);
    e10 = __builtin_amdgcn_readfirstlane(e10);
    e11 = __builtin_amdgcn_readfirstlane(e11);
    e20 = __builtin_amdgcn_readfirstlane(e20);
    e21 = __builtin_amdgcn_readfirstlane(e21);
    e30 = __builtin_amdgcn_readfirstlane(e30);
    e31 = __builtin_amdgcn_readfirstlane(e31);

    // ---- layer 1 as MFMA GEMM: C[16 samples][48 units], K-half per wave ----
    const int row = lane & 15;            // A row / B col within tile
    const int kg  = lane >> 4;            // k-group (8 elems each)
    const int sbase = blockIdx.x * SPB + g * SPW;
    const int kbase = half * KHALF;

    const float* aptr = x + (size_t)(sbase + row) * IN_DIM + kbase + kg * 8;

    const _Float16* bptr[3];
#pragma unroll
    for (int tt = 0; tt < 3; ++tt) {
        int u = tt * 16 + row;            // unit 0..47
        int e, o;
        if (u < HDIM)          { e = e10; o = u; }
        else if (u < 2 * HDIM) { e = e11; o = u - HDIM; }
        else                   { e = e10; o = 0; }   // pad cols: safe garbage
        bptr[tt] = Wh + ((size_t)e * HDIM + o) * IN_DIM + kbase + kg * 8;
    }

    f32x4 acc[3];
#pragma unroll
    for (int tt = 0; tt < 3; ++tt) acc[tt] = (f32x4){0.f, 0.f, 0.f, 0.f};

    if (half == 0) gemmLoop<12, 12>(aptr, bptr, kg, acc);  // k [0,384)
    else           gemmLoop<13, 12>(aptr, bptr, kg, acc);  // k [384,784), 16 tail

    // ---- C frag -> LDS: col = lane&15 (+16*tile), row = (lane>>4)*4 + reg ----
#pragma unroll
    for (int tt = 0; tt < 3; ++tt) {
        const int col = tt * 16 + row;
        if (col < 2 * HDIM) {
#pragma unroll
            for (int r = 0; r < 4; ++r)
                preLds[w][kg * 4 + r][col] = acc[tt][r];
        }
    }
    __syncthreads();

    // ---- epilogue: waves 0..3 only; 4 lanes per sample ----
    if (w < 4) {
        const int s    = lane >> 2;           // local sample 0..15
        const int ksub = lane & 3;

        float h1[HDIM];
#pragma unroll
        for (int c = 0; c < HDIM; ++c) {
            const float p0 = preLds[w][s][c]        + preLds[w + 4][s][c];
            const float p1 = preLds[w][s][HDIM + c] + preLds[w + 4][s][HDIM + c];
            h1[c] = fmaxf(p0 + b1[e10 * HDIM + c], 0.0f)
                  + m1 * fmaxf(p1 + b1[e11 * HDIM + c], 0.0f);
        }

        float my5[5];
#pragma unroll
        for (int j = 0; j < 5; ++j) {
            const int o = ksub * 5 + j;
            float a0 = b2[e20 * HDIM + o];
            float a1 = b2[e21 * HDIM + o];
            const float* r0 = W2 + ((size_t)e20 * HDIM + o) * HDIM;
            const float* r1 = W2 + ((size_t)e21 * HDIM + o) * HDIM;
#pragma unroll
            for (int c = 0; c < HDIM; ++c) {
                a0 += h1[c] * r0[c];
                a1 += h1[c] * r1[c];
            }
            my5[j] = fmaxf(a0, 0.0f) + m2 * fmaxf(a1, 0.0f);
        }
        float h2[HDIM];
        gather20(my5, ksub, h2);

#pragma unroll
        for (int j = 0; j < 5; ++j) {
            const int o = ksub * 5 + j;
            float a0 = b3[e30 * HDIM + o];
            float a1 = b3[e31 * HDIM + o];
            const float* r0 = W3 + ((size_t)e30 * HDIM + o) * HDIM;
            const float* r1 = W3 + ((size_t)e31 * HDIM + o) * HDIM;
#pragma unroll
            for (int c = 0; c < HDIM; ++c) {
                a0 += h2[c] * r0[c];
                a1 += h2[c] * r1[c];
            }
            my5[j] = fmaxf(a0, 0.0f) + m3 * fmaxf(a1, 0.0f);
        }
        float h3[HDIM];
        gather20(my5, ksub, h3);

        const int srow = sbase + s;
        const int c0 = ksub * 2;
        float ya = bl[c0], yb = bl[c0 + 1];
        const float* wr0 = Wl + c0 * HDIM;
        const float* wr1 = Wl + (c0 + 1) * HDIM;
#pragma unroll
        for (int o = 0; o < HDIM; ++o) {
            ya += h3[o] * wr0[o];
            yb += h3[o] * wr1[o];
        }
        float* op = out + (size_t)srow * NCLS;
        *reinterpret_cast<float2*>(op + c0) = make_float2(ya, yb);

        if (ksub == 0) {
            float y8 = bl[8], y9 = bl[9];
            const float* w8 = Wl + 8 * HDIM;
            const float* w9 = Wl + 9 * HDIM;
#pragma unroll
            for (int o = 0; o < HDIM; ++o) {
                y8 += h3[o] * w8[o];
                y9 += h3[o] * w9[o];
            }
            *reinterpret_cast<float2*>(op + 8) = make_float2(y8, y9);
        }
    }
}

extern "C" void kernel_launch(void* const* d_in, const int* in_sizes, int n_in,
                              void* d_out, int out_size, void* d_ws, size_t ws_size,
                              hipStream_t stream) {
    const float* x  = (const float*)d_in[0];
    const float* W1 = (const float*)d_in[1];
    const float* b1 = (const float*)d_in[2];
    const float* W2 = (const float*)d_in[3];
    const float* b2 = (const float*)d_in[4];
    const float* W3 = (const float*)d_in[5];
    const float* b3 = (const float*)d_in[6];
    const float* Wl = (const float*)d_in[7];
    const float* bl = (const float*)d_in[8];
    const int*   pw = (const int*)d_in[9];
    float* out = (float*)d_out;

    _Float16* Wh = (_Float16*)d_ws;      // 313.6 KB of scratch

    cvt_w1_kernel<<<(W1ELEMS / 4 + 255) / 256, 256, 0, stream>>>(W1, Wh);

    dim3 grid(BATCH / SPB);   // 1024 blocks x 8 waves = 8/SIMD
    pathnet_kernel<<<grid, THREADS, 0, stream>>>(x, Wh, b1, W2, b2,
                                                 W3, b3, Wl, bl, pw, out);
}

// Round 10
// 74.597 us; speedup vs baseline: 1.4787x; 1.4787x over previous
//
#include <hip/hip_runtime.h>

#define BATCH   65536
#define IN_DIM  784
#define HDIM    20
#define NCLS    10
#define THREADS 256           // 4 waves/block, full K per wave
#define SPW     16            // samples per wave (MFMA M)
#define SPB     64            // samples per block
#define NSTEPS  25            // 24 full 32-wide K-steps + one 16-wide tail
#define NFULLS  24
#define DA      6             // A-stage depth (HBM stream)
#define DB      3             // B-stage depth (L2-hot weights)
#define PSTRIDE 49            // LDS pre-act row stride (conflict-free)
#define W1ELEMS (10 * HDIM * IN_DIM)   // 156800

typedef __attribute__((ext_vector_type(2))) __fp16   fp16x2;   // cvt_pkrtz result type
typedef __attribute__((ext_vector_type(8))) _Float16 f16x8;    // MFMA operand type
typedef __attribute__((ext_vector_type(4))) float    f32x4;

typedef union { uint4 q; f16x8 v; } BFrag;
typedef union { fp16x2 h[4]; f16x8 v; } AFrag;
typedef union { fp16x2 h[2]; uint2 u; } Pack4;

// sorted(set(row))[:2] -> (e0, e1, mask). mask=0 when only one unique module.
__device__ __forceinline__ void route(const int* pw, bool is64, int row,
                                      int& e0, int& e1, float& m) {
    int v0, v1, v2;
    if (is64) {
        v0 = pw[(row * 3 + 0) * 2];
        v1 = pw[(row * 3 + 1) * 2];
        v2 = pw[(row * 3 + 2) * 2];
    } else {
        v0 = pw[row * 3 + 0];
        v1 = pw[row * 3 + 1];
        v2 = pw[row * 3 + 2];
    }
    int lo  = min(v0, min(v1, v2));
    int hi  = max(v0, max(v1, v2));
    int mid = v0 + v1 + v2 - lo - hi;
    e0 = lo;
    if (mid != lo)     { e1 = mid; m = 1.0f; }
    else if (hi != lo) { e1 = hi;  m = 1.0f; }
    else               { e1 = lo;  m = 0.0f; }
}

// gather the 4 per-lane 5-slices into a full 20-vector (static indexing)
__device__ __forceinline__ void gather20(const float my5[5], int ksub,
                                         float outv[HDIM]) {
    float r1[5];
#pragma unroll
    for (int j = 0; j < 5; ++j) r1[j] = __shfl_xor(my5[j], 1, 64);
    const bool b0 = (ksub & 1);
    float q[10];
#pragma unroll
    for (int j = 0; j < 5; ++j) {
        q[j]     = b0 ? r1[j]  : my5[j];
        q[5 + j] = b0 ? my5[j] : r1[j];
    }
    float r2[10];
#pragma unroll
    for (int j = 0; j < 10; ++j) r2[j] = __shfl_xor(q[j], 2, 64);
    const bool b1 = (ksub & 2);
#pragma unroll
    for (int j = 0; j < 10; ++j) {
        outv[j]      = b1 ? r2[j] : q[j];
        outv[10 + j] = b1 ? q[j]  : r2[j];
    }
}

// ---- pre-kernel: W1 (fp32) -> fp16, same [e][o][k] layout ----
__global__ __launch_bounds__(256)
void cvt_w1_kernel(const float* __restrict__ W1, _Float16* __restrict__ Wh) {
    const int i = (blockIdx.x * 256 + threadIdx.x) * 4;
    if (i < W1ELEMS) {
        const float4 v = *reinterpret_cast<const float4*>(W1 + i);
        Pack4 pk;
        pk.h[0] = __builtin_amdgcn_cvt_pkrtz(v.x, v.y);
        pk.h[1] = __builtin_amdgcn_cvt_pkrtz(v.z, v.w);
        *reinterpret_cast<uint2*>(Wh + i) = pk.u;
    }
}

// A-stage: 8 floats of x at k0. full=false -> 16-wide tail (kg<2 only).
__device__ __forceinline__ void loadA(bool full, int k0, int kg,
                                      const float* __restrict__ aptr,
                                      float a[8]) {
    if (full || kg < 2) {
        const float4 q0 = *reinterpret_cast<const float4*>(aptr + k0);
        const float4 q1 = *reinterpret_cast<const float4*>(aptr + k0 + 4);
        a[0] = q0.x; a[1] = q0.y; a[2] = q0.z; a[3] = q0.w;
        a[4] = q1.x; a[5] = q1.y; a[6] = q1.z; a[7] = q1.w;
    } else {
#pragma unroll
        for (int j = 0; j < 8; ++j) a[j] = 0.0f;
    }
}

// B-stage: 3 x uint4 of Wh at k0.
__device__ __forceinline__ void loadB(bool full, int k0, int kg,
                                      const _Float16* const bptr[3],
                                      uint4 b[3]) {
    if (full || kg < 2) {
#pragma unroll
        for (int tt = 0; tt < 3; ++tt)
            b[tt] = *reinterpret_cast<const uint4*>(bptr[tt] + k0);
    } else {
#pragma unroll
        for (int tt = 0; tt < 3; ++tt)
            b[tt] = make_uint4(0, 0, 0, 0);
    }
}

__device__ __forceinline__ void computeStep(const float a[8], const uint4 b[3],
                                            f32x4 acc[3]) {
    AFrag af;
#pragma unroll
    for (int j = 0; j < 4; ++j)
        af.h[j] = __builtin_amdgcn_cvt_pkrtz(a[2 * j], a[2 * j + 1]);
#pragma unroll
    for (int tt = 0; tt < 3; ++tt) {
        BFrag bf;
        bf.q = b[tt];
        acc[tt] = __builtin_amdgcn_mfma_f32_16x16x32_f16(af.v, bf.v, acc[tt], 0, 0, 0);
    }
}

__global__ __launch_bounds__(THREADS, 4)
void pathnet_kernel(const float* __restrict__ x,
                    const _Float16* __restrict__ Wh, const float* __restrict__ b1,
                    const float* __restrict__ W2, const float* __restrict__ b2,
                    const float* __restrict__ W3, const float* __restrict__ b3,
                    const float* __restrict__ Wl, const float* __restrict__ bl,
                    const int*   __restrict__ pathway,
                    float* __restrict__ out)
{
    __shared__ float preLds[4][SPW][PSTRIDE];   // 12.25 KB

    const int t    = threadIdx.x;
    const int lane = t & 63;
    const int w    = __builtin_amdgcn_readfirstlane(t >> 6);

    // ---- routing (uniform) ----
    bool is64 = ((pathway[1] | pathway[3] | pathway[5] | pathway[7]) == 0);
    int e10, e11, e20, e21, e30, e31;
    float m1, m2, m3;
    route(pathway, is64, 0, e10, e11, m1);
    route(pathway, is64, 1, e20, e21, m2);
    route(pathway, is64, 2, e30, e31, m3);
    e10 = __builtin_amdgcn_readfirstlane(e10);
    e11 = __builtin_amdgcn_readfirstlane(e11);
    e20 = __builtin_amdgcn_readfirstlane(e20);
    e21 = __builtin_amdgcn_readfirstlane(e21);
    e30 = __builtin_amdgcn_readfirstlane(e30);
    e31 = __builtin_amdgcn_readfirstlane(e31);

    // ---- layer 1 as MFMA GEMM: C[16 samples][48 units] per wave ----
    const int row = lane & 15;            // A row / B col within tile
    const int kg  = lane >> 4;            // k-group (8 elems each)
    const int sbase = blockIdx.x * SPB + w * SPW;

    const float* aptr = x + (size_t)(sbase + row) * IN_DIM + kg * 8;

    const _Float16* bptr[3];
#pragma unroll
    for (int tt = 0; tt < 3; ++tt) {
        int u = tt * 16 + row;            // unit 0..47
        int e, o;
        if (u < HDIM)          { e = e10; o = u; }
        else if (u < 2 * HDIM) { e = e11; o = u - HDIM; }
        else                   { e = e10; o = 0; }   // pad cols: safe garbage
        bptr[tt] = Wh + ((size_t)e * HDIM + o) * IN_DIM + kg * 8;
    }

    f32x4 acc[3];
#pragma unroll
    for (int tt = 0; tt < 3; ++tt) acc[tt] = (f32x4){0.f, 0.f, 0.f, 0.f};

    // ---- decoupled pipeline: A depth 6 (HBM), B depth 3 (L2) ----
    // Ring-buffer invariant: compute step i FIRST, then refill slot i%D
    // with step i+D (prefetch distance == depth is legal only in this order).
    float aSt[DA][8];
    uint4 bSt[DB][3];
#pragma unroll
    for (int j = 0; j < DA; ++j)
        loadA(j < NFULLS, j * 32, kg, aptr, aSt[j]);
#pragma unroll
    for (int j = 0; j < DB; ++j)
        loadB(j < NFULLS, j * 32, kg, bptr, bSt[j]);

#pragma unroll
    for (int i = 0; i < NSTEPS; ++i) {
        computeStep(aSt[i % DA], bSt[i % DB], acc);
        if (i + DA < NSTEPS)
            loadA(i + DA < NFULLS, (i + DA) * 32, kg, aptr, aSt[(i + DA) % DA]);
        if (i + DB < NSTEPS)
            loadB(i + DB < NFULLS, (i + DB) * 32, kg, bptr, bSt[(i + DB) % DB]);
    }

    // ---- C frag -> LDS: col = lane&15 (+16*tile), row = (lane>>4)*4 + reg ----
#pragma unroll
    for (int tt = 0; tt < 3; ++tt) {
        const int col = tt * 16 + row;
        if (col < 2 * HDIM) {
#pragma unroll
            for (int r = 0; r < 4; ++r)
                preLds[w][kg * 4 + r][col] = acc[tt][r];
        }
    }
    __syncthreads();

    // ---- epilogue: 4 lanes per sample ----
    const int s    = lane >> 2;           // local sample 0..15
    const int ksub = lane & 3;

    float h1[HDIM];
#pragma unroll
    for (int c = 0; c < HDIM; ++c) {
        const float p0 = preLds[w][s][c];
        const float p1 = preLds[w][s][HDIM + c];
        h1[c] = fmaxf(p0 + b1[e10 * HDIM + c], 0.0f)
              + m1 * fmaxf(p1 + b1[e11 * HDIM + c], 0.0f);
    }

    float my5[5];
#pragma unroll
    for (int j = 0; j < 5; ++j) {
        const int o = ksub * 5 + j;
        float a0 = b2[e20 * HDIM + o];
        float a1 = b2[e21 * HDIM + o];
        const float* r0 = W2 + ((size_t)e20 * HDIM + o) * HDIM;
        const float* r1 = W2 + ((size_t)e21 * HDIM + o) * HDIM;
#pragma unroll
        for (int c = 0; c < HDIM; ++c) {
            a0 += h1[c] * r0[c];
            a1 += h1[c] * r1[c];
        }
        my5[j] = fmaxf(a0, 0.0f) + m2 * fmaxf(a1, 0.0f);
    }
    float h2[HDIM];
    gather20(my5, ksub, h2);

#pragma unroll
    for (int j = 0; j < 5; ++j) {
        const int o = ksub * 5 + j;
        float a0 = b3[e30 * HDIM + o];
        float a1 = b3[e31 * HDIM + o];
        const float* r0 = W3 + ((size_t)e30 * HDIM + o) * HDIM;
        const float* r1 = W3 + ((size_t)e31 * HDIM + o) * HDIM;
#pragma unroll
        for (int c = 0; c < HDIM; ++c) {
            a0 += h2[c] * r0[c];
            a1 += h2[c] * r1[c];
        }
        my5[j] = fmaxf(a0, 0.0f) + m3 * fmaxf(a1, 0.0f);
    }
    float h3[HDIM];
    gather20(my5, ksub, h3);

    const int srow = sbase + s;
    const int c0 = ksub * 2;
    float ya = bl[c0], yb = bl[c0 + 1];
    const float* wr0 = Wl + c0 * HDIM;
    const float* wr1 = Wl + (c0 + 1) * HDIM;
#pragma unroll
    for (int o = 0; o < HDIM; ++o) {
        ya += h3[o] * wr0[o];
        yb += h3[o] * wr1[o];
    }
    float* op = out + (size_t)srow * NCLS;
    *reinterpret_cast<float2*>(op + c0) = make_float2(ya, yb);

    if (ksub == 0) {
        float y8 = bl[8], y9 = bl[9];
        const float* w8 = Wl + 8 * HDIM;
        const float* w9 = Wl + 9 * HDIM;
#pragma unroll
        for (int o = 0; o < HDIM; ++o) {
            y8 += h3[o] * w8[o];
            y9 += h3[o] * w9[o];
        }
        *reinterpret_cast<float2*>(op + 8) = make_float2(y8, y9);
    }
}

extern "C" void kernel_launch(void* const* d_in, const int* in_sizes, int n_in,
                              void* d_out, int out_size, void* d_ws, size_t ws_size,
                              hipStream_t stream) {
    const float* x  = (const float*)d_in[0];
    const float* W1 = (const float*)d_in[1];
    const float* b1 = (const float*)d_in[2];
    const float* W2 = (const float*)d_in[3];
    const float* b2 = (const float*)d_in[4];
    const float* W3 = (const float*)d_in[5];
    const float* b3 = (const float*)d_in[6];
    const float* Wl = (const float*)d_in[7];
    const float* bl = (const float*)d_in[8];
    const int*   pw = (const int*)d_in[9];
    float* out = (float*)d_out;

    _Float16* Wh = (_Float16*)d_ws;      // 313.6 KB of scratch

    cvt_w1_kernel<<<(W1ELEMS / 4 + 255) / 256, 256, 0, stream>>>(W1, Wh);

    dim3 grid(BATCH / SPB);   // 1024 blocks x 4 waves
    pathnet_kernel<<<grid, THREADS, 0, stream>>>(x, Wh, b1, W2, b2,
                                                 W3, b3, Wl, bl, pw, out);
}